// Round 5
// baseline (272.415 us; speedup 1.0000x reference)
//
#include <hip/hip_runtime.h>

// EdgeLoss: mean |sobel_mag(gray(pred)) - sobel_mag(gray(target))|
// pred/target: (32, 3, 512, 512) fp32, output: scalar fp32.
//
// R4 -> R5: every fused stencil variant lost to the compiler (R1/R2:
// register-minimized serial loads, 2.3 TB/s; R3/R4: unroll-hoist -> scratch
// spills, 88 MB scratch writes). Decompose into two shapes that saturate:
//   K1 gray: elementwise float4 stream (m13 pattern, 6.3 TB/s), fp16 out to ws.
//   K2 sobel: wave-per-row stencil on 33.5 MB fp16 gray (L3-resident),
//             18 independent 16B loads/thread, fp32 math, block reduce.
// Floor: (201 + 33.5 + 33.5) MB / 6.3 TB/s ~= 42.5 us.

typedef _Float16 half8 __attribute__((ext_vector_type(8)));
typedef _Float16 half4 __attribute__((ext_vector_type(4)));

#define BATCH 32
#define HH 512
#define WW 512
#define PLANE (HH * WW)                      // 262144 floats per channel plane
#define IMGPX ((size_t)BATCH * PLANE)        // 8,388,608 px per image set
#define GRAY_BYTES (2 * IMGPX * sizeof(_Float16))  // 33,554,432 B

__global__ void zero_out_kernel(float* out) { out[0] = 0.0f; }

// ---------------- K1: grayscale (elementwise stream) ----------------

struct RGB { float4 r, g, b; };

__device__ __forceinline__ RGB load_rgb(const float* __restrict__ base, unsigned u) {
    const unsigned bb  = u >> 16;            // batch (65536 float4-units per plane)
    const unsigned off = (u & 65535u) * 4u;  // float offset within plane
    const float* p = base + (size_t)bb * (3 * PLANE) + off;
    RGB x;
    x.r = *(const float4*)p;
    x.g = *(const float4*)(p + PLANE);
    x.b = *(const float4*)(p + 2 * PLANE);
    return x;
}

__device__ __forceinline__ half4 to_gray(const RGB& c) {
    half4 h;
    h[0] = (_Float16)(0.299f * c.r.x + 0.587f * c.g.x + 0.114f * c.b.x);
    h[1] = (_Float16)(0.299f * c.r.y + 0.587f * c.g.y + 0.114f * c.b.y);
    h[2] = (_Float16)(0.299f * c.r.z + 0.587f * c.g.z + 0.114f * c.b.z);
    h[3] = (_Float16)(0.299f * c.r.w + 0.587f * c.g.w + 0.114f * c.b.w);
    return h;
}

__global__ __launch_bounds__(256) void gray_kernel(
    const float* __restrict__ pred,
    const float* __restrict__ target,
    _Float16* __restrict__ gray)
{
    const unsigned tid = blockIdx.x * 256u + threadIdx.x;  // 0..1,048,575
    const unsigned S   = 1048576u;                         // units per pass
    const unsigned u0 = tid, u1 = tid + S;

    // All 12 loads issued before any consumption (independent streams).
    RGB a = load_rgb(pred,   u0);
    RGB b = load_rgb(pred,   u1);
    RGB c = load_rgb(target, u0);
    RGB d = load_rgb(target, u1);

    _Float16* gp = gray;            // pred gray plane
    _Float16* gt = gray + IMGPX;    // target gray plane
    *(half4*)(gp + (size_t)u0 * 4) = to_gray(a);
    *(half4*)(gp + (size_t)u1 * 4) = to_gray(b);
    *(half4*)(gt + (size_t)u0 * 4) = to_gray(c);
    *(half4*)(gt + (size_t)u1 * 4) = to_gray(d);
}

// ---------------- K2: Sobel + reduce (wave per row) ----------------

__device__ __forceinline__ void sobel_rows(
    const _Float16* __restrict__ row,   // base of row y within one gray image
    int x0, int xl, int xr, bool okm, bool okp, bool okL, bool okR,
    float ep[8])
{
    const _Float16* rm = okm ? row - WW : row;
    const _Float16* rp = okp ? row + WW : row;
    const half8 z8 = {(_Float16)0, (_Float16)0, (_Float16)0, (_Float16)0,
                      (_Float16)0, (_Float16)0, (_Float16)0, (_Float16)0};

    const half8 mC = okm ? *(const half8*)(rm + x0) : z8;
    const half8 mL = okm ? *(const half8*)(rm + xl) : z8;
    const half8 mR = okm ? *(const half8*)(rm + xr) : z8;
    const half8 cC = *(const half8*)(row + x0);
    const half8 cL = *(const half8*)(row + xl);
    const half8 cR = *(const half8*)(row + xr);
    const half8 pC = okp ? *(const half8*)(rp + x0) : z8;
    const half8 pL = okp ? *(const half8*)(rp + xl) : z8;
    const half8 pR = okp ? *(const half8*)(rp + xr) : z8;

    auto col = [&](const half8& L, const half8& C, const half8& R, int k) -> float {
        if (k < 0) return okL ? (float)L[7] : 0.0f;   // image col x0-1
        if (k > 7) return okR ? (float)R[0] : 0.0f;   // image col x0+8
        return (float)C[k];
    };

    #pragma unroll
    for (int j = 0; j < 8; ++j) {
        const float m0 = col(mL, mC, mR, j - 1), m1 = col(mL, mC, mR, j), m2 = col(mL, mC, mR, j + 1);
        const float c0 = col(cL, cC, cR, j - 1),                          c2 = col(cL, cC, cR, j + 1);
        const float q0 = col(pL, pC, pR, j - 1), q1 = col(pL, pC, pR, j), q2 = col(pL, pC, pR, j + 1);
        const float ex = (m2 - m0) + 2.0f * (c2 - c0) + (q2 - q0);
        const float ey = (q0 + 2.0f * q1 + q2) - (m0 + 2.0f * m1 + m2);
        ep[j] = sqrtf(ex * ex + ey * ey);
    }
}

__global__ __launch_bounds__(256) void sobel_kernel(
    const _Float16* __restrict__ gray, float* __restrict__ out)
{
    const int t    = threadIdx.x;
    const int lane = t & 63;
    const int wrow = blockIdx.x * 4 + (t >> 6);   // 0..16383 (32 imgs x 512 rows)
    const int y    = wrow & (HH - 1);

    const _Float16* gp = gray + (size_t)wrow * WW;   // pred row
    const _Float16* gt = gp + IMGPX;                 // target row

    const int x0 = lane * 8;
    const bool okm = (y > 0), okp = (y < HH - 1);
    const bool okL = (lane > 0), okR = (lane < 63);
    const int xl = okL ? x0 - 8 : 0;     // clamped; value masked by okL
    const int xr = okR ? x0 + 8 : x0;    // clamped; value masked by okR

    float ep[8], et[8];
    sobel_rows(gp, x0, xl, xr, okm, okp, okL, okR, ep);
    sobel_rows(gt, x0, xl, xr, okm, okp, okL, okR, et);

    float acc = 0.0f;
    #pragma unroll
    for (int j = 0; j < 8; ++j) acc += fabsf(ep[j] - et[j]);

    // wave shuffle -> cross-wave LDS -> one atomic per block
    #pragma unroll
    for (int off = 32; off > 0; off >>= 1)
        acc += __shfl_down(acc, off, 64);

    __shared__ float wsum[4];
    if (lane == 0) wsum[t >> 6] = acc;
    __syncthreads();
    if (t == 0) {
        const float s = wsum[0] + wsum[1] + wsum[2] + wsum[3];
        atomicAdd(out, s * (1.0f / (float)IMGPX));
    }
}

// ---------------- Fallback (ws too small): R2 fused kernel ----------------

#define TX 64
#define TY 32
#define LDS_W 72
#define LDS_W4 18
#define LDS_ROWS 34
#define SLOTS (LDS_ROWS * LDS_W4)

__global__ __launch_bounds__(256) void fused_kernel(
    const float* __restrict__ pred,
    const float* __restrict__ target,
    float* __restrict__ out)
{
    __shared__ float gp[LDS_ROWS * LDS_W];
    __shared__ float gt[LDS_ROWS * LDS_W];
    const int tid = threadIdx.x;
    const int x0 = blockIdx.x * TX;
    const int y0 = blockIdx.y * TY;
    const int b  = blockIdx.z;
    const size_t img = (size_t)HH * WW;
    const float* pbase = pred   + (size_t)b * 3 * img;
    const float* tbase = target + (size_t)b * 3 * img;
    float4* gp4 = (float4*)gp;
    float4* gt4 = (float4*)gt;
    #pragma unroll
    for (int tt = 0; tt < 3; ++tt) {
        const int i = tid + tt * 256;
        if (i < SLOTS) {
            const int row = i / LDS_W4;
            const int c   = i - row * LDS_W4;
            const int gy = y0 - 1 + row;
            const int gx = x0 - 4 + 4 * c;
            float4 vp = make_float4(0.f, 0.f, 0.f, 0.f);
            float4 vt = make_float4(0.f, 0.f, 0.f, 0.f);
            if (gy >= 0 && gy < HH && gx >= 0 && gx <= WW - 4) {
                const size_t o = (size_t)gy * WW + gx;
                const float4 pr = *(const float4*)(pbase + o);
                const float4 pg = *(const float4*)(pbase + o + img);
                const float4 pb = *(const float4*)(pbase + o + 2 * img);
                const float4 tr = *(const float4*)(tbase + o);
                const float4 tg = *(const float4*)(tbase + o + img);
                const float4 tb = *(const float4*)(tbase + o + 2 * img);
                vp.x = 0.299f*pr.x + 0.587f*pg.x + 0.114f*pb.x;
                vp.y = 0.299f*pr.y + 0.587f*pg.y + 0.114f*pb.y;
                vp.z = 0.299f*pr.z + 0.587f*pg.z + 0.114f*pb.z;
                vp.w = 0.299f*pr.w + 0.587f*pg.w + 0.114f*pb.w;
                vt.x = 0.299f*tr.x + 0.587f*tg.x + 0.114f*tb.x;
                vt.y = 0.299f*tr.y + 0.587f*tg.y + 0.114f*tb.y;
                vt.z = 0.299f*tr.z + 0.587f*tg.z + 0.114f*tb.z;
                vt.w = 0.299f*tr.w + 0.587f*tg.w + 0.114f*tb.w;
            }
            gp4[i] = vp;
            gt4[i] = vt;
        }
    }
    __syncthreads();
    const int tx = tid & 63;
    const int ty = tid >> 6;
    float lsum = 0.0f;
    #pragma unroll
    for (int i = 0; i < TY / 4; ++i) {
        const int ry = ty + 4 * i;
        const float* cp = &gp[ry * LDS_W + tx + 3];
        const float* ct = &gt[ry * LDS_W + tx + 3];
        float p00 = cp[0],       p01 = cp[1],           p02 = cp[2];
        float p10 = cp[LDS_W],                          p12 = cp[LDS_W + 2];
        float p20 = cp[2*LDS_W], p21 = cp[2*LDS_W + 1], p22 = cp[2*LDS_W + 2];
        float ex = (p02 - p00) + 2.0f * (p12 - p10) + (p22 - p20);
        float ey = (p20 - p00) + 2.0f * (p21 - p01) + (p22 - p02);
        float epv = sqrtf(ex * ex + ey * ey);
        float t00 = ct[0],       t01 = ct[1],           t02 = ct[2];
        float t10 = ct[LDS_W],                          t12 = ct[LDS_W + 2];
        float t20 = ct[2*LDS_W], t21 = ct[2*LDS_W + 1], t22 = ct[2*LDS_W + 2];
        float fx = (t02 - t00) + 2.0f * (t12 - t10) + (t22 - t20);
        float fy = (t20 - t00) + 2.0f * (t21 - t01) + (t22 - t02);
        float etv = sqrtf(fx * fx + fy * fy);
        lsum += fabsf(epv - etv);
    }
    #pragma unroll
    for (int off = 32; off > 0; off >>= 1)
        lsum += __shfl_down(lsum, off, 64);
    __shared__ float wsum[4];
    if ((tid & 63) == 0) wsum[ty] = lsum;
    __syncthreads();
    if (tid == 0) {
        const float s = wsum[0] + wsum[1] + wsum[2] + wsum[3];
        atomicAdd(out, s * (1.0f / (float)IMGPX));
    }
}

// ---------------- launch ----------------

extern "C" void kernel_launch(void* const* d_in, const int* in_sizes, int n_in,
                              void* d_out, int out_size, void* d_ws, size_t ws_size,
                              hipStream_t stream) {
    const float* pred   = (const float*)d_in[0];
    const float* target = (const float*)d_in[1];
    float* out = (float*)d_out;

    zero_out_kernel<<<1, 1, 0, stream>>>(out);

    if (ws_size >= GRAY_BYTES) {
        _Float16* gray = (_Float16*)d_ws;
        gray_kernel<<<4096, 256, 0, stream>>>(pred, target, gray);
        sobel_kernel<<<4096, 256, 0, stream>>>(gray, out);
    } else {
        dim3 grid(WW / TX, HH / TY, BATCH);
        fused_kernel<<<grid, 256, 0, stream>>>(pred, target, out);
    }
}

// Round 6
// 260.637 us; speedup vs baseline: 1.0452x; 1.0452x over previous
//
#include <hip/hip_runtime.h>

// EdgeLoss: mean |sobel_mag(gray(pred)) - sobel_mag(gray(target))|
// pred/target: (32, 3, 512, 512) fp32, output: scalar fp32.
// HBM floor: 201 MB read / 6.3 TB/s ~= 32 us.
//
// R5 -> R6: every load->register structure got compiler-serialized (VGPR
// 12/16/28, 2-3 TB/s). global_load_lds has NO register destination -> the
// wave fires its whole staging burst with zero intermediate waitcnts; MLP
// lives in the DMA queue, not VGPRs. Fused single kernel: 64x16 tile,
// stage raw RGB halo (18 rows x 72 cols x 6 planes = 31 KB) via DMA,
// border lanes exec-masked with pre-zeroed LDS slots, gray (fp32 LDS),
// Sobel, block reduce, one atomic. LDS 41.5 KB -> 3 blocks/CU.

#define BATCH 32
#define HH 512
#define WW 512
#define PLANE (HH * WW)

#define TLX 64                      // output tile width
#define TLY 16                      // output tile height
#define HR (TLY + 2)                // 18 halo rows (y0-1 .. y0+16)
#define HC4 18                      // float4 per halo row (x0-4 .. x0+67)
#define HCF (HC4 * 4)               // 72 floats per halo row
#define NPL 6                       // pred.rgb + target.rgb
#define RGB_SLOTS (NPL * HR * HC4)  // 1944 float4 slots (31104 B)
#define GRAYS (2 * HR * HCF)        // 2592 gray floats (10368 B)

__global__ void zero_out_kernel(float* out) { out[0] = 0.0f; }

__device__ __forceinline__ void async_load16(const float* g, float* l) {
    __builtin_amdgcn_global_load_lds(
        (const __attribute__((address_space(1))) unsigned int*)g,
        (__attribute__((address_space(3))) unsigned int*)l,
        16, 0, 0);
}

__global__ __launch_bounds__(256) void edge_loss_kernel(
    const float* __restrict__ pred,
    const float* __restrict__ target,
    float* __restrict__ out)
{
    __shared__ float rgbs[RGB_SLOTS * 4];   // raw RGB halo, flat (p, r, c4)
    __shared__ float grys[GRAYS];           // gray, flat (img, r, cf)
    __shared__ float wsum[4];

    const unsigned t    = threadIdx.x;
    const unsigned lane = t & 63u;
    const unsigned w    = t >> 6;
    const int x0 = blockIdx.x * TLX;
    const int y0 = blockIdx.y * TLY;
    const int b  = blockIdx.z;

    const float* pb = pred   + (size_t)b * 3 * PLANE;
    const float* tb = target + (size_t)b * 3 * PLANE;

    // ---- Phase 0: pre-zero LDS slots whose DMA will be skipped (borders).
    // Disjoint from DMA-written slots, so no barrier needed before Phase 1.
    if (x0 == 0 || y0 == 0 || x0 + TLX == WW || y0 + TLY == HH) {
        #pragma unroll
        for (unsigned k = 0; k < 8; ++k) {
            const unsigned s = t + k * 256u;
            if (s < RGB_SLOTS) {
                const unsigned rem = s % (HR * HC4);
                const int r   = rem / HC4;
                const int c   = rem % HC4;
                const int gy  = y0 - 1 + r;
                const int gxf = x0 - 4 + 4 * c;
                if (gy < 0 || gy >= HH || gxf < 0 || gxf > WW - 4) {
                    *(float4*)(rgbs + (size_t)s * 4) =
                        make_float4(0.f, 0.f, 0.f, 0.f);
                }
            }
        }
    }

    // ---- Phase 1: async DMA global->LDS, 16 B/lane, wave-uniform LDS base.
    // No VGPR destination -> all 8 issues go out back-to-back, no waitcnts.
    #pragma unroll
    for (unsigned k = 0; k < 8; ++k) {
        const unsigned sbase = k * 256u + w * 64u;  // wave-uniform slot base
        const unsigned s = sbase + lane;
        float* ldst = rgbs + (size_t)sbase * 4;     // HW adds lane*16
        if (s < RGB_SLOTS) {
            const unsigned p   = s / (HR * HC4);    // plane 0..5
            const unsigned rem = s % (HR * HC4);
            const int r   = rem / HC4;
            const int c   = rem % HC4;
            const int gy  = y0 - 1 + r;
            const int gxf = x0 - 4 + 4 * c;
            if (gy >= 0 && gy < HH && gxf >= 0 && gxf <= WW - 4) {
                const float* src = (p < 3 ? pb : tb)
                                 + (size_t)(p % 3) * PLANE
                                 + (size_t)gy * WW + gxf;
                async_load16(src, ldst);
            }
        }
    }
    __syncthreads();   // drains vmcnt (DMA) + lgkmcnt (zeroing)

    // ---- Phase 2: grayscale into LDS, same flat (img, r, cf) order.
    #pragma unroll
    for (unsigned k = 0; k < 11; ++k) {
        const unsigned g = t + k * 256u;
        if (g < GRAYS) {
            const unsigned i    = g / (HR * HCF);        // image 0/1
            const unsigned rrem = g - i * (HR * HCF);    // r*HCF + cf
            const unsigned base = i * 3 * (HR * HCF) + rrem;
            const float R = rgbs[base];
            const float G = rgbs[base + HR * HCF];
            const float B = rgbs[base + 2 * HR * HCF];
            grys[g] = 0.299f * R + 0.587f * G + 0.114f * B;
        }
    }
    __syncthreads();

    // ---- Phase 3: Sobel + |diff|; thread = one column, 4 rows.
    float acc = 0.0f;
    #pragma unroll
    for (unsigned k = 0; k < 4; ++k) {
        const unsigned ry = w + 4 * k;          // output row 0..15
        float mag[2];
        #pragma unroll
        for (int i = 0; i < 2; ++i) {
            const float* gm = grys + (i * HR + ry    ) * HCF + lane + 3;
            const float* gc = grys + (i * HR + ry + 1) * HCF + lane + 3;
            const float* gq = grys + (i * HR + ry + 2) * HCF + lane + 3;
            const float m0 = gm[0], m1 = gm[1], m2 = gm[2];
            const float c0 = gc[0],              c2 = gc[2];
            const float q0 = gq[0], q1 = gq[1], q2 = gq[2];
            const float ex = (m2 - m0) + 2.0f * (c2 - c0) + (q2 - q0);
            const float ey = (q0 + 2.0f * q1 + q2) - (m0 + 2.0f * m1 + m2);
            mag[i] = sqrtf(ex * ex + ey * ey);
        }
        acc += fabsf(mag[0] - mag[1]);
    }

    // ---- Reduce: wave shuffle -> cross-wave LDS -> one atomic per block.
    #pragma unroll
    for (int off = 32; off > 0; off >>= 1)
        acc += __shfl_down(acc, off, 64);
    if (lane == 0) wsum[w] = acc;
    __syncthreads();
    if (t == 0) {
        const float s = wsum[0] + wsum[1] + wsum[2] + wsum[3];
        atomicAdd(out, s * (1.0f / 8388608.0f));   // 32*512*512
    }
}

extern "C" void kernel_launch(void* const* d_in, const int* in_sizes, int n_in,
                              void* d_out, int out_size, void* d_ws, size_t ws_size,
                              hipStream_t stream) {
    const float* pred   = (const float*)d_in[0];
    const float* target = (const float*)d_in[1];
    float* out = (float*)d_out;

    // d_out is poisoned 0xAA before every timed launch -> zero it on-stream.
    zero_out_kernel<<<1, 1, 0, stream>>>(out);

    dim3 grid(WW / TLX, HH / TLY, BATCH);   // (8, 32, 32) = 8192 blocks
    edge_loss_kernel<<<grid, 256, 0, stream>>>(pred, target, out);
}

// Round 7
// 226.056 us; speedup vs baseline: 1.2051x; 1.1530x over previous
//
#include <hip/hip_runtime.h>

// EdgeLoss: mean |sobel_mag(gray(pred)) - sobel_mag(gray(target))|
// pred/target: (32, 3, 512, 512) fp32, output: scalar fp32.
// HBM floor: 201 MB read / 6.3 TB/s ~= 32 us.
//
// R6 -> R7: six rounds cluster at 2-3 TB/s for different proximate causes
// (compiler register-minimizes loads into serial chains at VGPR 12/16/28,
// or spill-pipelines, or DMA per-block overhead). This round: R2's LDS-tile
// structure (best so far, 86.6 us) with the staging loads forced into
// flight via inline asm: one volatile block issues 6 global_load_dwordx4
// back-to-back then a single s_waitcnt vmcnt(0); early-clobber outputs
// force 6 result quads (36 VGPRs) live. OOB halo handled by clamped
// addresses + post-select (loads always legal, no divergent guards).

typedef float f32x4 __attribute__((ext_vector_type(4)));

#define BATCH 32
#define HH 512
#define WW 512
#define TX 64
#define TY 32
#define LDS_W 72                  // floats per staged row (x0-4 .. x0+67)
#define LDS_W4 18                 // float4 per staged row
#define LDS_ROWS 34               // y0-1 .. y0+32
#define SLOTS (LDS_ROWS * LDS_W4) // 612 float4 slots per image

__global__ void zero_out_kernel(float* out) { out[0] = 0.0f; }

// Issue 6 independent 16B loads, then ONE wait. The compiler cannot
// serialize (single asm block) and cannot drop results (early-clobber).
__device__ __forceinline__ void load6(
    const float* a0, const float* a1, const float* a2,
    const float* a3, const float* a4, const float* a5,
    f32x4& r0, f32x4& r1, f32x4& r2, f32x4& r3, f32x4& r4, f32x4& r5)
{
    asm volatile(
        "global_load_dwordx4 %0, %6, off\n\t"
        "global_load_dwordx4 %1, %7, off\n\t"
        "global_load_dwordx4 %2, %8, off\n\t"
        "global_load_dwordx4 %3, %9, off\n\t"
        "global_load_dwordx4 %4, %10, off\n\t"
        "global_load_dwordx4 %5, %11, off\n\t"
        "s_waitcnt vmcnt(0)"
        : "=&v"(r0), "=&v"(r1), "=&v"(r2), "=&v"(r3), "=&v"(r4), "=&v"(r5)
        : "v"(a0), "v"(a1), "v"(a2), "v"(a3), "v"(a4), "v"(a5));
}

__global__ __launch_bounds__(256) void edge_loss_kernel(
    const float* __restrict__ pred,
    const float* __restrict__ target,
    float* __restrict__ out)
{
    __shared__ float gp[LDS_ROWS * LDS_W];
    __shared__ float gt[LDS_ROWS * LDS_W];

    const int tid = threadIdx.x;
    const int x0 = blockIdx.x * TX;
    const int y0 = blockIdx.y * TY;
    const int b  = blockIdx.z;

    const size_t img = (size_t)HH * WW;
    const float* pbase = pred   + (size_t)b * 3 * img;
    const float* tbase = target + (size_t)b * 3 * img;

    float4* gp4 = (float4*)gp;
    float4* gt4 = (float4*)gt;

    // ---- Stage grayscale halo tile (72 x 34), forced-batched loads ----
    #pragma unroll
    for (int t3 = 0; t3 < 3; ++t3) {
        const int i = tid + t3 * 256;
        if (i < SLOTS) {
            const int row = i / LDS_W4;          // 0..33
            const int c   = i - row * LDS_W4;    // 0..17
            const int gy = y0 - 1 + row;
            const int gx = x0 - 4 + 4 * c;
            const bool ok = (gy >= 0) && (gy < HH) && (gx >= 0) && (gx <= WW - 4);
            // Clamped (always-legal) address; result discarded when !ok.
            const int sy = min(max(gy, 0), HH - 1);
            const int sx = min(max(gx, 0), WW - 4);
            const size_t o = (size_t)sy * WW + sx;

            f32x4 pr, pg, pb, tr, tg, tb;
            load6(pbase + o, pbase + o + img, pbase + o + 2 * img,
                  tbase + o, tbase + o + img, tbase + o + 2 * img,
                  pr, pg, pb, tr, tg, tb);

            float4 vp, vt;
            vp.x = 0.299f * pr.x + 0.587f * pg.x + 0.114f * pb.x;
            vp.y = 0.299f * pr.y + 0.587f * pg.y + 0.114f * pb.y;
            vp.z = 0.299f * pr.z + 0.587f * pg.z + 0.114f * pb.z;
            vp.w = 0.299f * pr.w + 0.587f * pg.w + 0.114f * pb.w;
            vt.x = 0.299f * tr.x + 0.587f * tg.x + 0.114f * tb.x;
            vt.y = 0.299f * tr.y + 0.587f * tg.y + 0.114f * tb.y;
            vt.z = 0.299f * tr.z + 0.587f * tg.z + 0.114f * tb.z;
            vt.w = 0.299f * tr.w + 0.587f * tg.w + 0.114f * tb.w;
            if (!ok) {
                vp = make_float4(0.f, 0.f, 0.f, 0.f);
                vt = make_float4(0.f, 0.f, 0.f, 0.f);
            }
            gp4[i] = vp;
            gt4[i] = vt;
        }
    }
    __syncthreads();

    // ---- Compute: 64 wide x 4 tall, each thread does 8 rows ----
    const int tx = tid & 63;
    const int ty = tid >> 6;
    float lsum = 0.0f;

    #pragma unroll
    for (int i = 0; i < TY / 4; ++i) {
        const int ry = ty + 4 * i;                     // output row within tile
        const float* cp = &gp[ry * LDS_W + tx + 3];    // window top-left
        const float* ct = &gt[ry * LDS_W + tx + 3];

        float p00 = cp[0],         p01 = cp[1],             p02 = cp[2];
        float p10 = cp[LDS_W],                              p12 = cp[LDS_W + 2];
        float p20 = cp[2*LDS_W],   p21 = cp[2*LDS_W + 1],   p22 = cp[2*LDS_W + 2];
        float ex = (p02 - p00) + 2.0f * (p12 - p10) + (p22 - p20);
        float ey = (p20 - p00) + 2.0f * (p21 - p01) + (p22 - p02);
        float ep = sqrtf(ex * ex + ey * ey);

        float t00 = ct[0],         t01 = ct[1],             t02 = ct[2];
        float t10 = ct[LDS_W],                              t12 = ct[LDS_W + 2];
        float t20 = ct[2*LDS_W],   t21 = ct[2*LDS_W + 1],   t22 = ct[2*LDS_W + 2];
        float fx = (t02 - t00) + 2.0f * (t12 - t10) + (t22 - t20);
        float fy = (t20 - t00) + 2.0f * (t21 - t01) + (t22 - t02);
        float et = sqrtf(fx * fx + fy * fy);

        lsum += fabsf(ep - et);
    }

    // ---- Reduce: wave shuffle -> cross-wave LDS -> one atomic per block ----
    #pragma unroll
    for (int off = 32; off > 0; off >>= 1)
        lsum += __shfl_down(lsum, off, 64);

    __shared__ float wsum[4];
    if ((tid & 63) == 0) wsum[ty] = lsum;
    __syncthreads();
    if (tid == 0) {
        const float s = wsum[0] + wsum[1] + wsum[2] + wsum[3];
        const float inv_n = 1.0f / ((float)BATCH * HH * WW);
        atomicAdd(out, s * inv_n);
    }
}

extern "C" void kernel_launch(void* const* d_in, const int* in_sizes, int n_in,
                              void* d_out, int out_size, void* d_ws, size_t ws_size,
                              hipStream_t stream) {
    const float* pred   = (const float*)d_in[0];
    const float* target = (const float*)d_in[1];
    float* out = (float*)d_out;

    // d_out is poisoned 0xAA before every timed launch -> zero it on-stream.
    zero_out_kernel<<<1, 1, 0, stream>>>(out);

    dim3 grid(WW / TX, HH / TY, BATCH);  // (8, 16, 32) = 4096 blocks
    edge_loss_kernel<<<grid, 256, 0, stream>>>(pred, target, out);
}